// Round 13
// baseline (358.451 us; speedup 1.0000x reference)
//
#include <hip/hip_runtime.h>

// ---------------------------------------------------------------------------
// Fully-fused Sparse-MMoE forward for MI355X (gfx950), v13.
// B=65536, D=512, E=8, H1=64, H2=32, O=64, T=2, K=2.
//
// v13: X staged as fp32 in LDS via global_load_lds (no VGPR round-trip,
//      coalesced; source pre-swizzled so reads are bank-conflict-free).
//      Gating reads exact fp32 x from LDS (16-lane broadcast) -> no fr[]
//      registers, no partial-reduce phases. GEMM1 A-frags: fp32 LDS ->
//      bf16 via v_perm_b32 truncation. 4 barriers. Register peak ~87.
//
// moe_prep:  weight repack fp32 -> bf16 MFMA B-fragment order (+ wgt fp32
//            transpose copy, + gacc/cnt zeroing).
// moe_fused: 2048 blocks x 512 thr (8 waves = 8 experts), 32 tokens/block.
// ---------------------------------------------------------------------------

typedef short bfrag __attribute__((ext_vector_type(8)));   // 8 bf16 = 4 VGPRs
typedef float facc  __attribute__((ext_vector_type(4)));   // 4 f32 accum

#define MFMA16(a, b, c) __builtin_amdgcn_mfma_f32_16x16x32_bf16((a), (b), (c), 0, 0, 0)

typedef const __attribute__((address_space(1))) unsigned int guint;
typedef __attribute__((address_space(3))) unsigned int luint;

__device__ __forceinline__ unsigned short bfbits(float f) {
  unsigned int u = __builtin_bit_cast(unsigned int, f);
  u += 0x7FFFu + ((u >> 16) & 1u);          // RNE
  return (unsigned short)(u >> 16);
}
__device__ __forceinline__ unsigned pack2(float a, float b) {
  return (unsigned)bfbits(a) | ((unsigned)bfbits(b) << 16);
}
__device__ __forceinline__ float bf2f(unsigned short s) {
  unsigned int u = ((unsigned int)s) << 16;
  return __builtin_bit_cast(float, u);
}
__device__ __forceinline__ unsigned fb(float f) {
  return __builtin_bit_cast(unsigned, f);
}
// pack2 by truncation (RTZ): dst = {hi16(lo), hi16(hi)<<16} via v_perm_b32
__device__ __forceinline__ unsigned packtr(float lo, float hi) {
  return __builtin_amdgcn_perm(fb(hi), fb(lo), 0x07060302u);
}

// LDS map (bytes):
//  [0,     65536) : X tile [32 tok][512] fp32 pitch 2048, 16B-granule
//                   XOR-swizzle ((tok&7)<<4). After B2 the first 32 KB is
//                   reused as 8 expert chunks of 4 KB:
//                     H1 [32][64]sigma pitch 128 -> H2 [32][32]sigma2
//                     pitch 64 (front 2 KB) -> Out [32][64]sigma pitch 128
//  [65536, 68096) : G logits [32 tok][20] f32 (pitch 20)
//  [68096, 69120) : recs [32 tok][2 task] float4 {g1,g2,e1,e2}
//  [69120, 69248) : lacc [32] f32
#define G_OFF   65536
#define R_OFF   68096
#define A_OFF   69120
#define SM_SIZE 69248

__global__ __launch_bounds__(512, 4) void moe_fused(
    const float* __restrict__ x,
    const float* __restrict__ b_gates,
    const float* __restrict__ wgt,      // [16 te][512 k] f32, te = t*8+e
    const float* __restrict__ b1,
    const float* __restrict__ b2,
    const float* __restrict__ b3,
    const bfrag* __restrict__ w1f,
    const bfrag* __restrict__ w2f,
    const bfrag* __restrict__ w3f,
    float* __restrict__ gacc_out,       // [32] + cnt at +32
    float* __restrict__ y)
{
  __shared__ alignas(16) char smem[SM_SIZE];
  const int tid = threadIdx.x;
  const int wave = tid >> 6, lane = tid & 63;
  const int q = lane & 15, g = lane >> 4;
  const int e = wave;                       // 8 waves = 8 experts
  const unsigned cb = (unsigned)e * 4096u;  // own chunk (after B2)

  if (tid < 32) ((float*)(smem + A_OFF))[tid] = 0.f;

  // ---------- stage X fp32 -> LDS via DMA, pre-swizzled source ----------
  {
    const char* xb = (const char*)(x + (size_t)blockIdx.x * 32 * 512);
    #pragma unroll
    for (int it = 0; it < 8; ++it) {
      unsigned off = (unsigned)(it * 8192 + tid * 16);
      unsigned so  = off ^ (((off >> 11) & 7u) << 4);
      __builtin_amdgcn_global_load_lds((guint*)(xb + so), (luint*)(smem + off), 16, 0, 0);
    }
  }

  // hoist first GEMM1 B-fragments (cheap: +16 regs, big headroom now)
  const bfrag* w1e = w1f + e * 4096 + lane;
  bfrag Bc[4];
  #pragma unroll
  for (int n = 0; n < 4; ++n) Bc[n] = w1e[n * 64];
  __syncthreads();                                   // B0: X staged

  // ---------- gating: thread (tok=tid>>4, te=tid&15), exact fp32 ----------
  {
    const int tok = tid >> 4, te = tid & 15;
    const float4* wrow = (const float4*)(wgt + te * 512);
    const unsigned xrow = (unsigned)(tok * 2048);
    const unsigned sx = ((unsigned)(tok & 7)) << 4;
    float a0 = 0.f, a1 = 0.f, a2 = 0.f, a3 = 0.f;
    #pragma unroll 4
    for (int j = 0; j < 128; ++j) {
      float4 x4 = *(const float4*)(smem + ((xrow + j * 16) ^ sx));
      float4 w4 = wrow[j];
      a0 = fmaf(x4.x, w4.x, a0);
      a1 = fmaf(x4.y, w4.y, a1);
      a2 = fmaf(x4.z, w4.z, a2);
      a3 = fmaf(x4.w, w4.w, a3);
    }
    ((float*)(smem + G_OFF))[tok * 20 + te] = (a0 + a1) + (a2 + a3) + b_gates[te];
  }
  __syncthreads();                                   // B1: logits ready

  // ---------- top-2 + softmax (wave 0 only; other waves go to GEMM1) ------
  if (tid < 64) {
    int tok = tid >> 1, task = tid & 1;
    const float* Gr = (const float*)(smem + G_OFF) + tok * 20 + task * 8;
    float l[8];
    #pragma unroll
    for (int ee = 0; ee < 8; ++ee) l[ee] = Gr[ee];
    float v1 = l[0]; int e1 = 0;
    #pragma unroll
    for (int ee = 1; ee < 8; ++ee) { if (l[ee] > v1) { v1 = l[ee]; e1 = ee; } }
    float v2 = -3.4e38f; int e2 = 0;
    #pragma unroll
    for (int ee = 0; ee < 8; ++ee) {
      if (ee != e1 && l[ee] > v2) { v2 = l[ee]; e2 = ee; }
    }
    float g1 = 1.f / (1.f + __expf(v2 - v1));
    float g2 = 1.f - g1;
    float4 rec;
    rec.x = g1; rec.y = g2;
    rec.z = __int_as_float(e1); rec.w = __int_as_float(e2);
    ((float4*)(smem + R_OFF))[tok * 2 + task] = rec;
    float* lacc = (float*)(smem + A_OFF);
    atomicAdd(lacc + task * 8 + e1, g1);
    atomicAdd(lacc + task * 8 + e2, g2);
    atomicAdd(lacc + 16 + task * 8 + e1, 1.f);
    atomicAdd(lacc + 16 + task * 8 + e2, 1.f);
  }

  // ---------------- GEMM1: 32 tok x 64 h1, K=512 ----------------
  // A-frags from fp32 LDS (2x ds_read_b128 + 4x v_perm truncation-pack)
  facc acc[2][4];
  #pragma unroll
  for (int m = 0; m < 2; ++m)
    #pragma unroll
    for (int n = 0; n < 4; ++n) acc[m][n] = (facc)0.f;

  {
    const unsigned sw = ((unsigned)(q & 7)) << 4;
    bfrag Bn[4];
    #pragma unroll
    for (int ks = 0; ks < 16; ++ks) {
      if (ks < 15) {
        #pragma unroll
        for (int n = 0; n < 4; ++n) Bn[n] = w1e[(ks + 1) * 256 + n * 64];
      }
      #pragma unroll
      for (int m = 0; m < 2; ++m) {
        unsigned ba = (unsigned)((m * 16 + q) * 2048 + ks * 128 + g * 32);
        float4 f0 = *(const float4*)(smem + (ba ^ sw));
        float4 f1 = *(const float4*)(smem + ((ba + 16) ^ sw));
        uint4 pk;
        pk.x = packtr(f0.x, f0.y);
        pk.y = packtr(f0.z, f0.w);
        pk.z = packtr(f1.x, f1.y);
        pk.w = packtr(f1.z, f1.w);
        bfrag A = __builtin_bit_cast(bfrag, pk);
        #pragma unroll
        for (int n = 0; n < 4; ++n) acc[m][n] = MFMA16(A, Bc[n], acc[m][n]);
      }
      if (ks < 15) {
        #pragma unroll
        for (int n = 0; n < 4; ++n) Bc[n] = Bn[n];
      }
    }
  }

  // preload GEMM2 weights + bias (in flight across barrier + H1 phase)
  bfrag W2r[4];
  #pragma unroll
  for (int i = 0; i < 4; ++i) W2r[i] = w2f[e * 256 + i * 64 + lane];
  float b2v0 = b2[e * 32 + q];
  float b2v1 = b2[e * 32 + 16 + q];
  __syncthreads();                                   // B2: X dead

  // ---------------- H1 -> own chunk (sigma: s = q*4+n) ----------------
  {
    float bv[4];
    #pragma unroll
    for (int n = 0; n < 4; ++n) bv[n] = b1[e * 64 + n * 16 + q];
    #pragma unroll
    for (int m = 0; m < 2; ++m) {
      #pragma unroll
      for (int j = 0; j < 4; ++j) {
        float v0 = fmaxf(acc[m][0][j] + bv[0], 0.f);
        float v1 = fmaxf(acc[m][1][j] + bv[1], 0.f);
        float v2 = fmaxf(acc[m][2][j] + bv[2], 0.f);
        float v3 = fmaxf(acc[m][3][j] + bv[3], 0.f);
        int rr = m * 16 + g * 4 + j;
        unsigned byte = cb + (((unsigned)(rr * 128 + q * 8)) ^ ((unsigned)(rr & 7) << 4));
        uint2 pk; pk.x = pack2(v0, v1); pk.y = pack2(v2, v3);
        *(uint2*)(smem + byte) = pk;
      }
    }
  }

  // ---------------- GEMM2: K=64 (sigma), N=32 ----------------
  {
    facc a2[2][2];
    #pragma unroll
    for (int m = 0; m < 2; ++m) { a2[m][0] = (facc)0.f; a2[m][1] = (facc)0.f; }
    #pragma unroll
    for (int ks = 0; ks < 2; ++ks) {
      #pragma unroll
      for (int m = 0; m < 2; ++m) {
        unsigned ba = cb + (((unsigned)((m * 16 + q) * 128 + ks * 64 + g * 16)) ^ ((unsigned)(q & 7) << 4));
        bfrag A = *(const bfrag*)(smem + ba);
        a2[m][0] = MFMA16(A, W2r[ks * 2], a2[m][0]);
        a2[m][1] = MFMA16(A, W2r[ks * 2 + 1], a2[m][1]);
      }
    }
    // preload GEMM3 weights + bias
    bfrag W3r[4];
    #pragma unroll
    for (int n = 0; n < 4; ++n) W3r[n] = w3f[e * 256 + n * 64 + lane];
    float b3v[4];
    #pragma unroll
    for (int n = 0; n < 4; ++n) b3v[n] = b3[e * 64 + n * 16 + q];

    // H2 -> own chunk front (sigma2: s = q*2+n)
    #pragma unroll
    for (int m = 0; m < 2; ++m) {
      #pragma unroll
      for (int j = 0; j < 4; ++j) {
        float v0 = fmaxf(a2[m][0][j] + b2v0, 0.f);
        float v1 = fmaxf(a2[m][1][j] + b2v1, 0.f);
        int rr = m * 16 + g * 4 + j;
        unsigned byte = cb + (((unsigned)(rr * 64 + q * 4)) ^ ((unsigned)(rr & 7) << 4));
        *(unsigned int*)(smem + byte) = pack2(v0, v1);
      }
    }

    // ---------------- GEMM3: K=32 (sigma2), N=64 ----------------
    facc a3[2][4];
    #pragma unroll
    for (int m = 0; m < 2; ++m)
      #pragma unroll
      for (int n = 0; n < 4; ++n) a3[m][n] = (facc)0.f;
    #pragma unroll
    for (int m = 0; m < 2; ++m) {
      unsigned ba = cb + (((unsigned)((m * 16 + q) * 64 + g * 16)) ^ ((unsigned)(q & 7) << 4));
      bfrag A = *(const bfrag*)(smem + ba);
      #pragma unroll
      for (int n = 0; n < 4; ++n) a3[m][n] = MFMA16(A, W3r[n], a3[m][n]);
    }
    // Out -> full own chunk (sigma: s = q*4+n), after all H2 reads (in-order)
    #pragma unroll
    for (int m = 0; m < 2; ++m) {
      #pragma unroll
      for (int j = 0; j < 4; ++j) {
        float v0 = fmaxf(a3[m][0][j] + b3v[0], 0.f);
        float v1 = fmaxf(a3[m][1][j] + b3v[1], 0.f);
        float v2 = fmaxf(a3[m][2][j] + b3v[2], 0.f);
        float v3 = fmaxf(a3[m][3][j] + b3v[3], 0.f);
        int rr = m * 16 + g * 4 + j;
        unsigned byte = cb + (((unsigned)(rr * 128 + q * 8)) ^ ((unsigned)(rr & 7) << 4));
        uint2 pk; pk.x = pack2(v0, v1); pk.y = pack2(v2, v3);
        *(uint2*)(smem + byte) = pk;
      }
    }
  }
  __syncthreads();                                   // B3: chunks complete

  // ---------- gacc atomics first (overlap with combine's y-writes) ----------
  if (tid < 32) atomicAdd(gacc_out + tid, ((float*)(smem + A_OFF))[tid]);

  // ---------------- combine: recs + weighted sum ----------------
  {
    int tok = tid >> 4, u = tid & 15;
    size_t trow = (size_t)blockIdx.x * 32 + tok;
    unsigned obyte = ((unsigned)(tok * 128 + u * 8)) ^ ((unsigned)(tok & 7) << 4);
    const float4* recs = (const float4*)(smem + R_OFF);
    #pragma unroll
    for (int tt = 0; tt < 2; ++tt) {
      float4 rec = recs[tok * 2 + tt];
      float g1 = rec.x, g2 = rec.y;
      int e1 = __float_as_int(rec.z), e2 = __float_as_int(rec.w);
      uint2 o1 = *(const uint2*)(smem + e1 * 4096 + obyte);
      uint2 o2 = *(const uint2*)(smem + e2 * 4096 + obyte);
      unsigned short s1[4] = { (unsigned short)o1.x, (unsigned short)(o1.x >> 16),
                               (unsigned short)o1.y, (unsigned short)(o1.y >> 16) };
      unsigned short s2[4] = { (unsigned short)o2.x, (unsigned short)(o2.x >> 16),
                               (unsigned short)o2.y, (unsigned short)(o2.y >> 16) };
      float* yt = y + (size_t)tt * 4194304 + trow * 64;
      #pragma unroll
      for (int w = 0; w < 4; ++w) {
        // storage col s = 4u+w -> actual col c = w*16 + u
        yt[w * 16 + u] = g1 * bf2f(s1[w]) + g2 * bf2f(s2[w]);
      }
    }
  }

  // ---------- last-block-done: compute cv^2 loss in-kernel ----------
  if (tid == 0) {
    __threadfence();                     // drains this wave's gacc atomics
    unsigned* cnt = (unsigned*)(gacc_out + 32);
    unsigned old = atomicAdd(cnt, 1u);
    if (old == gridDim.x - 1) {
      float loss = 0.f;
      #pragma unroll
      for (int a = 0; a < 4; ++a) {      // [imp t0][imp t1][load t0][load t1]
        float v[8]; float mm = 0.f;
        #pragma unroll
        for (int i = 0; i < 8; ++i) {
          v[i] = __hip_atomic_load(gacc_out + a * 8 + i, __ATOMIC_RELAXED,
                                   __HIP_MEMORY_SCOPE_AGENT);
          mm += v[i];
        }
        mm *= 0.125f;
        float var = 0.f;
        #pragma unroll
        for (int i = 0; i < 8; ++i) { float d = v[i] - mm; var += d * d; }
        loss += (var * (1.f / 7.f)) / (mm * mm + 1e-10f);
      }
      y[8388608] = 0.01f * loss;
    }
  }
}

// ============================ weight repack ================================
//  w1f: [E][16ks][4n][64lane]       B = W1[k][h], h = n*16+q
//  w2f: [E][2ks][2n][64]            K in H1-sigma order: h = (s&3)*16 + (s>>2)
//  w3f: [E][1][4n][64]              K in H2-sigma order: h = (s&1)*16 + (s>>1)
//  wgt: [16 te][512 k] f32          te = t*8+e (exact copy for fp32 gating)
//  also zeroes gacc[32] + done-counter
__global__ __launch_bounds__(256) void moe_prep(
    const float* __restrict__ W1, const float* __restrict__ W2,
    const float* __restrict__ W3, const float* __restrict__ wg,
    bfrag* __restrict__ w1f, bfrag* __restrict__ w2f,
    bfrag* __restrict__ w3f, float* __restrict__ wgt,
    float* __restrict__ gacc)
{
  int tid = blockIdx.x * 256 + threadIdx.x;
  bfrag o;
  if (tid < 32768) {
    int lane = tid & 63, nt = (tid >> 6) & 3, ks = (tid >> 8) & 15, e = tid >> 12;
    int q = lane & 15, g = lane >> 4;
    int hcol = nt * 16 + q;
    #pragma unroll
    for (int j = 0; j < 8; ++j) {
      int k = ks * 32 + g * 8 + j;
      o[j] = (short)bfbits(W1[((e * 512 + k) * 64) + hcol]);
    }
    w1f[tid] = o;
  } else if (tid < 34816) {
    int idx = tid - 32768;
    int lane = idx & 63, nt = (idx >> 6) & 1, ks = (idx >> 7) & 1, e = idx >> 8;
    int q = lane & 15, g = lane >> 4;
    int n = nt * 16 + q;
    #pragma unroll
    for (int j = 0; j < 8; ++j) {
      int s = ks * 32 + g * 8 + j;
      int hh = (s & 3) * 16 + (s >> 2);
      o[j] = (short)bfbits(W2[(e * 64 + hh) * 32 + n]);
    }
    w2f[idx] = o;
  } else if (tid < 36864) {
    int idx = tid - 34816;
    int lane = idx & 63, nt = (idx >> 6) & 3, e = idx >> 8;
    int q = lane & 15, g = lane >> 4;
    int ocol = nt * 16 + q;
    #pragma unroll
    for (int j = 0; j < 8; ++j) {
      int s = g * 8 + j;
      int hh = (s & 1) * 16 + (s >> 1);
      o[j] = (short)bfbits(W3[(e * 32 + hh) * 64 + ocol]);
    }
    w3f[idx] = o;
  } else if (tid < 45056) {
    int idx = tid - 36864;            // te = idx>>9, k = idx&511
    int te = idx >> 9, k = idx & 511;
    wgt[idx] = wg[(((te >> 3) * 512) + k) * 8 + (te & 7)];
  } else if (tid < 45089) {
    gacc[tid - 45056] = 0.f;          // gacc[0..31] + cnt (word 32)
  }
}

extern "C" void kernel_launch(void* const* d_in, const int* in_sizes, int n_in,
                              void* d_out, int out_size, void* d_ws, size_t ws_size,
                              hipStream_t stream) {
  const float* x  = (const float*)d_in[0];
  const float* wg = (const float*)d_in[1];
  const float* bg = (const float*)d_in[2];
  const float* W1 = (const float*)d_in[3];
  const float* b1 = (const float*)d_in[4];
  const float* W2 = (const float*)d_in[5];
  const float* b2 = (const float*)d_in[6];
  const float* W3 = (const float*)d_in[7];
  const float* b3 = (const float*)d_in[8];
  float* y = (float*)d_out;

  char* ws = (char*)d_ws;
  float*  gacc = (float*)ws;                 // 132 B (32 accum + cnt)
  bfrag*  w1f  = (bfrag*)(ws + 256);         // 524288 B
  bfrag*  w2f  = (bfrag*)(ws + 524544);      // 32768 B
  bfrag*  w3f  = (bfrag*)(ws + 557312);      // 32768 B
  float*  wgt  = (float*)(ws + 590080);      // 32768 B

  moe_prep<<<177, 256, 0, stream>>>(W1, W2, W3, wg, w1f, w2f, w3f, wgt, gacc);
  moe_fused<<<2048, 512, 0, stream>>>(x, bg, wgt, b1, b2, b3, w1f, w2f, w3f, gacc, y);
}

// Round 14
// 248.181 us; speedup vs baseline: 1.4443x; 1.4443x over previous
//
#include <hip/hip_runtime.h>

// ---------------------------------------------------------------------------
// Fully-fused Sparse-MMoE forward for MI355X (gfx950), v14.
// B=65536, D=512, E=8, H1=64, H2=32, O=64, T=2, K=2.
//
// v14: gating (VALU, fp32 from registers) INTERLEAVED with GEMM1 (MFMA)
//      in one 16-step loop -> the two pipes overlap instead of running
//      serially.  32 tok/block (v9 mapping, fr[8]), X staged to LDS before
//      the loop, gating partials in a separate LDS region.  (512,4) cap.
//
// moe_prep:  weight repack fp32 -> bf16 MFMA B-fragment order (+ wgt fp32
//            transpose copy, + gacc/cnt zeroing).
// moe_fused: 2048 blocks x 512 thr (8 waves = 8 experts), 32 tokens/block.
// ---------------------------------------------------------------------------

typedef short bfrag __attribute__((ext_vector_type(8)));   // 8 bf16 = 4 VGPRs
typedef float facc  __attribute__((ext_vector_type(4)));   // 4 f32 accum

#define MFMA16(a, b, c) __builtin_amdgcn_mfma_f32_16x16x32_bf16((a), (b), (c), 0, 0, 0)

__device__ __forceinline__ unsigned short bfbits(float f) {
  unsigned int u = __builtin_bit_cast(unsigned int, f);
  u += 0x7FFFu + ((u >> 16) & 1u);          // RNE
  return (unsigned short)(u >> 16);
}
__device__ __forceinline__ unsigned pack2(float a, float b) {
  return (unsigned)bfbits(a) | ((unsigned)bfbits(b) << 16);
}
__device__ __forceinline__ float bf2f(unsigned short s) {
  unsigned int u = ((unsigned int)s) << 16;
  return __builtin_bit_cast(float, u);
}

// LDS map (bytes):
//  [0,     32768) : X tile [32 tok][512] bf16 pitch 1024, ^((tok&7)<<4);
//                   after B1 reused as 8 expert chunks of 4 KB:
//                     H1 [32][64]sigma pitch 128 -> H2 [32][32]sigma2
//                     pitch 64 (front 2 KB) -> Out [32][64]sigma pitch 128
//  [32768, 65536) : gating partials [16 c=(w,kh)][32 tok][16 slot] f32
//  [65536, 67712) : G logits [32 tok][17] f32 (pitch 17)
//  [67712, 68736) : recs [32 tok][2 task] float4 {g1,g2,e1,e2}
//  [68736, 68864) : lacc [32] f32
#define P_OFF   32768
#define G_OFF   65536
#define R_OFF   67712
#define A_OFF   68736
#define SM_SIZE 68864

__global__ __launch_bounds__(512, 4) void moe_fused(
    const float* __restrict__ x,
    const float* __restrict__ b_gates,
    const float* __restrict__ wgt,      // [16 te][512 k] f32, te = t*8+e
    const float* __restrict__ b1,
    const float* __restrict__ b2,
    const float* __restrict__ b3,
    const bfrag* __restrict__ w1f,
    const bfrag* __restrict__ w2f,
    const bfrag* __restrict__ w3f,
    float* __restrict__ gacc_out,       // [32] + cnt at +32
    float* __restrict__ y)
{
  __shared__ alignas(16) char smem[SM_SIZE];
  const int tid = threadIdx.x;
  const int wave = tid >> 6, lane = tid & 63;
  const int q = lane & 15, g = lane >> 4;
  const int e = wave;                       // 8 waves = 8 experts
  const unsigned cb = (unsigned)e * 4096u;  // own chunk (after B1)
  const int tok = lane & 31;                // token (0..31)
  const int kh  = lane >> 5;                // k-half within wave's 64-chunk

  if (tid < 32) ((float*)(smem + A_OFF))[tid] = 0.f;

  // ---------- load x: thread (wave,kh,tok) holds k [wave*64+kh*32, +32) ----
  const float* src = x + (size_t)blockIdx.x * 32 * 512 + tok * 512 + wave * 64 + kh * 32;
  float4 fr[8];
  #pragma unroll
  for (int j = 0; j < 8; ++j) fr[j] = ((const float4*)src)[j];

  // ---------- stage X tile from registers (bf16, swizzled) ----------
  #pragma unroll
  for (int p = 0; p < 4; ++p) {
    uint4 v;
    v.x = pack2(fr[2 * p].x, fr[2 * p].y);
    v.y = pack2(fr[2 * p].z, fr[2 * p].w);
    v.z = pack2(fr[2 * p + 1].x, fr[2 * p + 1].y);
    v.w = pack2(fr[2 * p + 1].z, fr[2 * p + 1].w);
    unsigned byte = ((unsigned)(tok * 1024 + wave * 128 + kh * 64 + p * 16)) ^ ((unsigned)(tok & 7) << 4);
    *(uint4*)(smem + byte) = v;
  }

  // hoist GEMM1 first B-fragments (in flight across the barrier)
  const bfrag* w1e = w1f + e * 4096 + lane;
  bfrag Bc[4];
  #pragma unroll
  for (int n = 0; n < 4; ++n) Bc[n] = w1e[n * 64];
  __syncthreads();                                   // B0: X staged

  // ============ INTERLEAVED: gating dots (VALU) + GEMM1 (MFMA) ============
  facc acc[2][4];
  #pragma unroll
  for (int m = 0; m < 2; ++m)
    #pragma unroll
    for (int n = 0; n < 4; ++n) acc[m][n] = (facc)0.f;

  {
    // per-lane gating weight base: only 2 distinct addresses per wave
    const float* wbase = wgt + wave * 64 + kh * 32;
    float* pp = (float*)(smem + P_OFF) + ((wave * 2 + kh) * 32 + tok) * 16;
    bfrag Bn[4];
    #pragma unroll
    for (int st = 0; st < 16; ++st) {
      // ---- GEMM1 B prefetch for next step ----
      if (st < 15) {
        #pragma unroll
        for (int n = 0; n < 4; ++n) Bn[n] = w1e[(st + 1) * 256 + n * 64];
      }
      // ---- gating dot te=st: 32 fp32 fmaf from registers ----
      {
        const float4* wr = (const float4*)(wbase + st * 512);
        float a0 = 0.f, a1 = 0.f, a2 = 0.f, a3 = 0.f;
        #pragma unroll
        for (int j = 0; j < 8; ++j) {
          float4 w4 = wr[j];
          a0 = fmaf(fr[j].x, w4.x, a0);
          a1 = fmaf(fr[j].y, w4.y, a1);
          a2 = fmaf(fr[j].z, w4.z, a2);
          a3 = fmaf(fr[j].w, w4.w, a3);
        }
        pp[(st + (tok >> 1)) & 15] = (a0 + a1) + (a2 + a3);
      }
      // ---- GEMM1 MFMA step ks=st ----
      #pragma unroll
      for (int m = 0; m < 2; ++m) {
        unsigned ba = ((unsigned)((m * 16 + q) * 1024 + st * 64 + g * 16)) ^ ((unsigned)(q & 7) << 4);
        bfrag A = *(const bfrag*)(smem + ba);
        acc[m][0] = MFMA16(A, Bc[0], acc[m][0]);
        acc[m][1] = MFMA16(A, Bc[1], acc[m][1]);
        acc[m][2] = MFMA16(A, Bc[2], acc[m][2]);
        acc[m][3] = MFMA16(A, Bc[3], acc[m][3]);
      }
      if (st < 15) {
        #pragma unroll
        for (int n = 0; n < 4; ++n) Bc[n] = Bn[n];
      }
    }
  }

  // preload GEMM2 weights + bias (in flight across barrier + reduce + H1)
  bfrag W2r[4];
  #pragma unroll
  for (int i = 0; i < 4; ++i) W2r[i] = w2f[e * 256 + i * 64 + lane];
  float b2v0 = b2[e * 32 + q];
  float b2v1 = b2[e * 32 + 16 + q];
  __syncthreads();                                   // B1: partials + X reads done

  // ---------- reduce 16 (wave,kh) partials -> G logits (pitch 17) ----------
  {
    int tk = tid >> 4, te = tid & 15;
    const float* pb = (const float*)(smem + P_OFF) + tk * 16 + ((te + (tk >> 1)) & 15);
    float s = 0.f;
    #pragma unroll
    for (int c = 0; c < 16; ++c) s += pb[c * 512];
    ((float*)(smem + G_OFF))[tk * 17 + te] = s + b_gates[te];
  }

  // ---------- H1 -> own chunk (sigma: s = q*4+n), X region dead ----------
  {
    float bv[4];
    #pragma unroll
    for (int n = 0; n < 4; ++n) bv[n] = b1[e * 64 + n * 16 + q];
    #pragma unroll
    for (int m = 0; m < 2; ++m) {
      #pragma unroll
      for (int j = 0; j < 4; ++j) {
        float v0 = fmaxf(acc[m][0][j] + bv[0], 0.f);
        float v1 = fmaxf(acc[m][1][j] + bv[1], 0.f);
        float v2 = fmaxf(acc[m][2][j] + bv[2], 0.f);
        float v3 = fmaxf(acc[m][3][j] + bv[3], 0.f);
        int rr = m * 16 + g * 4 + j;
        unsigned byte = cb + (((unsigned)(rr * 128 + q * 8)) ^ ((unsigned)(rr & 7) << 4));
        uint2 pk; pk.x = pack2(v0, v1); pk.y = pack2(v2, v3);
        *(uint2*)(smem + byte) = pk;
      }
    }
  }
  __syncthreads();                                   // B2: G logits complete

  // ---------- top-2 + softmax -> recs + imp/load atomics (wave 0) ----------
  if (tid < 64) {
    int ttok = tid >> 1, task = tid & 1;
    const float* Gr = (const float*)(smem + G_OFF) + ttok * 17 + task * 8;
    float l[8];
    #pragma unroll
    for (int ee = 0; ee < 8; ++ee) l[ee] = Gr[ee];
    float v1 = l[0]; int e1 = 0;
    #pragma unroll
    for (int ee = 1; ee < 8; ++ee) { if (l[ee] > v1) { v1 = l[ee]; e1 = ee; } }
    float v2 = -3.4e38f; int e2 = 0;
    #pragma unroll
    for (int ee = 0; ee < 8; ++ee) {
      if (ee != e1 && l[ee] > v2) { v2 = l[ee]; e2 = ee; }
    }
    float g1 = 1.f / (1.f + __expf(v2 - v1));
    float g2 = 1.f - g1;
    float4 rec;
    rec.x = g1; rec.y = g2;
    rec.z = __int_as_float(e1); rec.w = __int_as_float(e2);
    ((float4*)(smem + R_OFF))[ttok * 2 + task] = rec;
    float* lacc = (float*)(smem + A_OFF);
    atomicAdd(lacc + task * 8 + e1, g1);
    atomicAdd(lacc + task * 8 + e2, g2);
    atomicAdd(lacc + 16 + task * 8 + e1, 1.f);
    atomicAdd(lacc + 16 + task * 8 + e2, 1.f);
  }

  // ---------------- GEMM2: K=64 (sigma), N=32 ----------------
  {
    facc a2[2][2];
    #pragma unroll
    for (int m = 0; m < 2; ++m) { a2[m][0] = (facc)0.f; a2[m][1] = (facc)0.f; }
    #pragma unroll
    for (int ks = 0; ks < 2; ++ks) {
      #pragma unroll
      for (int m = 0; m < 2; ++m) {
        unsigned ba = cb + (((unsigned)((m * 16 + q) * 128 + ks * 64 + g * 16)) ^ ((unsigned)(q & 7) << 4));
        bfrag A = *(const bfrag*)(smem + ba);
        a2[m][0] = MFMA16(A, W2r[ks * 2], a2[m][0]);
        a2[m][1] = MFMA16(A, W2r[ks * 2 + 1], a2[m][1]);
      }
    }
    // preload GEMM3 weights + bias
    bfrag W3r[4];
    #pragma unroll
    for (int n = 0; n < 4; ++n) W3r[n] = w3f[e * 256 + n * 64 + lane];
    float b3v[4];
    #pragma unroll
    for (int n = 0; n < 4; ++n) b3v[n] = b3[e * 64 + n * 16 + q];

    // H2 -> own chunk front (sigma2: s = q*2+n)
    #pragma unroll
    for (int m = 0; m < 2; ++m) {
      #pragma unroll
      for (int j = 0; j < 4; ++j) {
        float v0 = fmaxf(a2[m][0][j] + b2v0, 0.f);
        float v1 = fmaxf(a2[m][1][j] + b2v1, 0.f);
        int rr = m * 16 + g * 4 + j;
        unsigned byte = cb + (((unsigned)(rr * 64 + q * 4)) ^ ((unsigned)(rr & 7) << 4));
        *(unsigned int*)(smem + byte) = pack2(v0, v1);
      }
    }

    // ---------------- GEMM3: K=32 (sigma2), N=64 ----------------
    facc a3[2][4];
    #pragma unroll
    for (int m = 0; m < 2; ++m)
      #pragma unroll
      for (int n = 0; n < 4; ++n) a3[m][n] = (facc)0.f;
    #pragma unroll
    for (int m = 0; m < 2; ++m) {
      unsigned ba = cb + (((unsigned)((m * 16 + q) * 64 + g * 16)) ^ ((unsigned)(q & 7) << 4));
      bfrag A = *(const bfrag*)(smem + ba);
      #pragma unroll
      for (int n = 0; n < 4; ++n) a3[m][n] = MFMA16(A, W3r[n], a3[m][n]);
    }
    // Out -> full own chunk (sigma: s = q*4+n), after all H2 reads (in-order)
    #pragma unroll
    for (int m = 0; m < 2; ++m) {
      #pragma unroll
      for (int j = 0; j < 4; ++j) {
        float v0 = fmaxf(a3[m][0][j] + b3v[0], 0.f);
        float v1 = fmaxf(a3[m][1][j] + b3v[1], 0.f);
        float v2 = fmaxf(a3[m][2][j] + b3v[2], 0.f);
        float v3 = fmaxf(a3[m][3][j] + b3v[3], 0.f);
        int rr = m * 16 + g * 4 + j;
        unsigned byte = cb + (((unsigned)(rr * 128 + q * 8)) ^ ((unsigned)(rr & 7) << 4));
        uint2 pk; pk.x = pack2(v0, v1); pk.y = pack2(v2, v3);
        *(uint2*)(smem + byte) = pk;
      }
    }
  }
  __syncthreads();                                   // B3: chunks + recs + lacc

  // ---------- gacc atomics first (overlap with combine's y-writes) ----------
  if (tid < 32) atomicAdd(gacc_out + tid, ((float*)(smem + A_OFF))[tid]);

  // ---------------- combine: recs + weighted sum ----------------
  {
    int ct = tid >> 4, u = tid & 15;
    size_t trow = (size_t)blockIdx.x * 32 + ct;
    unsigned obyte = ((unsigned)(ct * 128 + u * 8)) ^ ((unsigned)(ct & 7) << 4);
    const float4* recs = (const float4*)(smem + R_OFF);
    #pragma unroll
    for (int tt = 0; tt < 2; ++tt) {
      float4 rec = recs[ct * 2 + tt];
      float g1 = rec.x, g2 = rec.y;
      int e1 = __float_as_int(rec.z), e2 = __float_as_int(rec.w);
      uint2 o1 = *(const uint2*)(smem + e1 * 4096 + obyte);
      uint2 o2 = *(const uint2*)(smem + e2 * 4096 + obyte);
      unsigned short s1[4] = { (unsigned short)o1.x, (unsigned short)(o1.x >> 16),
                               (unsigned short)o1.y, (unsigned short)(o1.y >> 16) };
      unsigned short s2[4] = { (unsigned short)o2.x, (unsigned short)(o2.x >> 16),
                               (unsigned short)o2.y, (unsigned short)(o2.y >> 16) };
      float* yt = y + (size_t)tt * 4194304 + trow * 64;
      #pragma unroll
      for (int w = 0; w < 4; ++w) {
        // storage col s = 4u+w -> actual col c = w*16 + u
        yt[w * 16 + u] = g1 * bf2f(s1[w]) + g2 * bf2f(s2[w]);
      }
    }
  }

  // ---------- last-block-done: compute cv^2 loss in-kernel ----------
  if (tid == 0) {
    __threadfence();                     // drains this wave's gacc atomics
    unsigned* cnt = (unsigned*)(gacc_out + 32);
    unsigned old = atomicAdd(cnt, 1u);
    if (old == gridDim.x - 1) {
      float loss = 0.f;
      #pragma unroll
      for (int a = 0; a < 4; ++a) {      // [imp t0][imp t1][load t0][load t1]
        float v[8]; float mm = 0.f;
        #pragma unroll
        for (int i = 0; i < 8; ++i) {
          v[i] = __hip_atomic_load(gacc_out + a * 8 + i, __ATOMIC_RELAXED,
                                   __HIP_MEMORY_SCOPE_AGENT);
          mm += v[i];
        }
        mm *= 0.125f;
        float var = 0.f;
        #pragma unroll
        for (int i = 0; i < 8; ++i) { float d = v[i] - mm; var += d * d; }
        loss += (var * (1.f / 7.f)) / (mm * mm + 1e-10f);
      }
      y[8388608] = 0.01f * loss;
    }
  }
}

// ============================ weight repack ================================
//  w1f: [E][16ks][4n][64lane]       B = W1[k][h], h = n*16+q
//  w2f: [E][2ks][2n][64]            K in H1-sigma order: h = (s&3)*16 + (s>>2)
//  w3f: [E][1][4n][64]              K in H2-sigma order: h = (s&1)*16 + (s>>1)
//  wgt: [16 te][512 k] f32          te = t*8+e (exact copy for fp32 gating)
//  also zeroes gacc[32] + done-counter
__global__ __launch_bounds__(256) void moe_prep(
    const float* __restrict__ W1, const float* __restrict__ W2,
    const float* __restrict__ W3, const float* __restrict__ wg,
    bfrag* __restrict__ w1f, bfrag* __restrict__ w2f,
    bfrag* __restrict__ w3f, float* __restrict__ wgt,
    float* __restrict__ gacc)
{
  int tid = blockIdx.x * 256 + threadIdx.x;
  bfrag o;
  if (tid < 32768) {
    int lane = tid & 63, nt = (tid >> 6) & 3, ks = (tid >> 8) & 15, e = tid >> 12;
    int q = lane & 15, g = lane >> 4;
    int hcol = nt * 16 + q;
    #pragma unroll
    for (int j = 0; j < 8; ++j) {
      int k = ks * 32 + g * 8 + j;
      o[j] = (short)bfbits(W1[((e * 512 + k) * 64) + hcol]);
    }
    w1f[tid] = o;
  } else if (tid < 34816) {
    int idx = tid - 32768;
    int lane = idx & 63, nt = (idx >> 6) & 1, ks = (idx >> 7) & 1, e = idx >> 8;
    int q = lane & 15, g = lane >> 4;
    int n = nt * 16 + q;
    #pragma unroll
    for (int j = 0; j < 8; ++j) {
      int s = ks * 32 + g * 8 + j;
      int hh = (s & 3) * 16 + (s >> 2);
      o[j] = (short)bfbits(W2[(e * 64 + hh) * 32 + n]);
    }
    w2f[idx] = o;
  } else if (tid < 36864) {
    int idx = tid - 34816;
    int lane = idx & 63, nt = (idx >> 6) & 3, e = idx >> 8;
    int q = lane & 15, g = lane >> 4;
    int ocol = nt * 16 + q;
    #pragma unroll
    for (int j = 0; j < 8; ++j) {
      int s = g * 8 + j;
      int hh = (s & 1) * 16 + (s >> 1);
      o[j] = (short)bfbits(W3[(e * 32 + hh) * 64 + ocol]);
    }
    w3f[idx] = o;
  } else if (tid < 45056) {
    int idx = tid - 36864;            // te = idx>>9, k = idx&511
    int te = idx >> 9, k = idx & 511;
    wgt[idx] = wg[(((te >> 3) * 512) + k) * 8 + (te & 7)];
  } else if (tid < 45089) {
    gacc[tid - 45056] = 0.f;          // gacc[0..31] + cnt (word 32)
  }
}

extern "C" void kernel_launch(void* const* d_in, const int* in_sizes, int n_in,
                              void* d_out, int out_size, void* d_ws, size_t ws_size,
                              hipStream_t stream) {
  const float* x  = (const float*)d_in[0];
  const float* wg = (const float*)d_in[1];
  const float* bg = (const float*)d_in[2];
  const float* W1 = (const float*)d_in[3];
  const float* b1 = (const float*)d_in[4];
  const float* W2 = (const float*)d_in[5];
  const float* b2 = (const float*)d_in[6];
  const float* W3 = (const float*)d_in[7];
  const float* b3 = (const float*)d_in[8];
  float* y = (float*)d_out;

  char* ws = (char*)d_ws;
  float*  gacc = (float*)ws;                 // 132 B (32 accum + cnt)
  bfrag*  w1f  = (bfrag*)(ws + 256);         // 524288 B
  bfrag*  w2f  = (bfrag*)(ws + 524544);      // 32768 B
  bfrag*  w3f  = (bfrag*)(ws + 557312);      // 32768 B
  float*  wgt  = (float*)(ws + 590080);      // 32768 B

  moe_prep<<<177, 256, 0, stream>>>(W1, W2, W3, wg, w1f, w2f, w3f, wgt, gacc);
  moe_fused<<<2048, 512, 0, stream>>>(x, bg, wgt, b1, b2, b3, w1f, w2f, w3f, gacc, y);
}

// Round 15
// 119.097 us; speedup vs baseline: 3.0097x; 2.0838x over previous
//
#include <hip/hip_runtime.h>

// ---------------------------------------------------------------------------
// Fully-fused Sparse-MMoE forward for MI355X (gfx950), v15.
// B=65536, D=512, E=8, H1=64, H2=32, O=64, T=2, K=2.
//
// v15 = v8 verbatim (measured best: 87.9us) + s_setprio(1) around the MFMA
//       clusters (T5: helps when resident blocks are phase-shifted; zero
//       register cost -> cannot re-trigger the v9-v14 spill failure mode).
//
// moe_prep:  weight repack fp32 -> bf16 MFMA B-fragment order (+ wgt fp32
//            transpose copy, + gacc/cnt zeroing).
// moe_fused: 1024 blocks x 512 thr (8 waves = 8 experts), 64 tokens/block.
//            fp32 gating (scalar weight loads) -> top-2 -> bf16 MFMA MLP.
// ---------------------------------------------------------------------------

typedef short bfrag __attribute__((ext_vector_type(8)));   // 8 bf16 = 4 VGPRs
typedef float facc  __attribute__((ext_vector_type(4)));   // 4 f32 accum

#define MFMA16(a, b, c) __builtin_amdgcn_mfma_f32_16x16x32_bf16((a), (b), (c), 0, 0, 0)

__device__ __forceinline__ unsigned short bfbits(float f) {
  unsigned int u = __builtin_bit_cast(unsigned int, f);
  u += 0x7FFFu + ((u >> 16) & 1u);          // RNE
  return (unsigned short)(u >> 16);
}
__device__ __forceinline__ unsigned pack2(float a, float b) {
  return (unsigned)bfbits(a) | ((unsigned)bfbits(b) << 16);
}
__device__ __forceinline__ float bf2f(unsigned short s) {
  unsigned int u = ((unsigned int)s) << 16;
  return __builtin_bit_cast(float, u);
}

// LDS map (bytes):
//  [0,     65536) : gating partials [8w][64tok][16te] f32 (first 32 KB)
//                   -> X tile [64][512] bf16 pitch 1024, XOR ((r&7)<<4)
//                   -> H1/H2/Out wave-private chunks of 8 KB per expert
//  [65536, 70656) : G logits [64][20] f32
//  [70656, 72704) : rec [64 tok][2 task] float4 {g1,g2,e1,e2}
//  [72704, 72832) : lacc [32] f32 (imp t0|imp t1|load t0|load t1)
#define G_OFF   65536
#define R_OFF   70656
#define A_OFF   72704
#define SM_SIZE 72832

__global__ __launch_bounds__(512, 4) void moe_fused(
    const float* __restrict__ x,
    const float* __restrict__ b_gates,
    const float* __restrict__ wgt,      // [16 te][512 k] f32, te = t*8+e
    const float* __restrict__ b1,
    const float* __restrict__ b2,
    const float* __restrict__ b3,
    const bfrag* __restrict__ w1f,
    const bfrag* __restrict__ w2f,
    const bfrag* __restrict__ w3f,
    float* __restrict__ gacc_out,       // [32] + cnt at +32
    float* __restrict__ y)
{
  __shared__ alignas(16) char smem[SM_SIZE];
  const int tid = threadIdx.x;
  const int wave = tid >> 6, lane = tid & 63;
  const int q = lane & 15, g = lane >> 4;
  const int e = wave;                       // 8 waves = 8 experts
  const unsigned cb = (unsigned)e * 8192u;  // own H1/Out chunk

  if (tid < 32) ((float*)(smem + A_OFF))[tid] = 0.f;

  // ---------- load x: lane = token, wave = k-chunk [64w, 64w+64) ----------
  const float* src = x + (size_t)blockIdx.x * 64 * 512 + lane * 512 + wave * 64;
  float4 fr[16];
  #pragma unroll
  for (int j = 0; j < 16; ++j) fr[j] = ((const float4*)src)[j];

  // ---------- gating partial dots: exact fp32, wave-uniform scalar weights ----------
  {
    int wu = __builtin_amdgcn_readfirstlane(wave);
    const float* wbase = wgt + wu * 64;
    float* pp = (float*)(smem + wave * 4096 + lane * 64);
    #pragma unroll
    for (int te = 0; te < 16; ++te) {
      const float* wrow = wbase + te * 512;
      float a0 = 0.f, a1 = 0.f, a2 = 0.f, a3 = 0.f;
      #pragma unroll
      for (int j = 0; j < 16; ++j) {
        a0 = fmaf(fr[j].x, wrow[j * 4 + 0], a0);
        a1 = fmaf(fr[j].y, wrow[j * 4 + 1], a1);
        a2 = fmaf(fr[j].z, wrow[j * 4 + 2], a2);
        a3 = fmaf(fr[j].w, wrow[j * 4 + 3], a3);
      }
      pp[(te + lane) & 15] = (a0 + a1) + (a2 + a3);   // te-rotation: conflict-free
    }
  }
  __syncthreads();                                   // B0

  // ---------- reduce 8 wave-partials -> G logits ----------
  #pragma unroll
  for (int i0 = 0; i0 < 2; ++i0) {
    int i = i0 * 512 + tid;
    int tok = i >> 4, te = i & 15;
    const float* pb = (const float*)smem + tok * 16 + ((te + tok) & 15);
    float s = 0.f;
    #pragma unroll
    for (int w2 = 0; w2 < 8; ++w2) s += pb[w2 * 1024];
    ((float*)(smem + G_OFF))[tok * 20 + te] = s + b_gates[te];
  }
  __syncthreads();                                   // B1 (partials dead)

  // ---------- stage X tile from registers (overwrites partials region) ----------
  #pragma unroll
  for (int p = 0; p < 8; ++p) {
    uint4 v;
    v.x = pack2(fr[2 * p].x, fr[2 * p].y);
    v.y = pack2(fr[2 * p].z, fr[2 * p].w);
    v.z = pack2(fr[2 * p + 1].x, fr[2 * p + 1].y);
    v.w = pack2(fr[2 * p + 1].z, fr[2 * p + 1].w);
    unsigned byte = ((unsigned)(lane * 1024 + wave * 128 + p * 16)) ^ ((unsigned)(lane & 7) << 4);
    *(uint4*)(smem + byte) = v;
  }

  // ---------- top-2 + softmax -> LDS recs + imp/load atomics ----------
  if (tid < 128) {
    int tok = tid >> 1, task = tid & 1;
    const float* Gr = (const float*)(smem + G_OFF) + tok * 20 + task * 8;
    float l[8];
    #pragma unroll
    for (int ee = 0; ee < 8; ++ee) l[ee] = Gr[ee];
    float v1 = l[0]; int e1 = 0;
    #pragma unroll
    for (int ee = 1; ee < 8; ++ee) { if (l[ee] > v1) { v1 = l[ee]; e1 = ee; } }
    float v2 = -3.4e38f; int e2 = 0;
    #pragma unroll
    for (int ee = 0; ee < 8; ++ee) {
      if (ee != e1 && l[ee] > v2) { v2 = l[ee]; e2 = ee; }
    }
    float g1 = 1.f / (1.f + __expf(v2 - v1));
    float g2 = 1.f - g1;
    float4 rec;
    rec.x = g1; rec.y = g2;
    rec.z = __int_as_float(e1); rec.w = __int_as_float(e2);
    ((float4*)(smem + R_OFF))[tok * 2 + task] = rec;
    float* lacc = (float*)(smem + A_OFF);
    atomicAdd(lacc + task * 8 + e1, g1);
    atomicAdd(lacc + task * 8 + e2, g2);
    atomicAdd(lacc + 16 + task * 8 + e1, 1.f);
    atomicAdd(lacc + 16 + task * 8 + e2, 1.f);
  }
  __syncthreads();                                   // B2 (X staged)

  // ---------------- GEMM1: 64 tok x 64 h1, K=512, depth-1 B prefetch ------
  facc acc[4][4];
  #pragma unroll
  for (int m = 0; m < 4; ++m)
    #pragma unroll
    for (int n = 0; n < 4; ++n) acc[m][n] = (facc)0.f;

  const bfrag* w1e = w1f + e * 4096 + lane;
  bfrag Bc[4], Bn[4];
  #pragma unroll
  for (int n = 0; n < 4; ++n) Bc[n] = w1e[n * 64];
  #pragma unroll
  for (int ks = 0; ks < 16; ++ks) {
    if (ks < 15) {
      #pragma unroll
      for (int n = 0; n < 4; ++n) Bn[n] = w1e[(ks + 1) * 256 + n * 64];
    }
    __builtin_amdgcn_s_setprio(1);
    #pragma unroll
    for (int m = 0; m < 4; ++m) {
      unsigned ba = ((unsigned)((m * 16 + q) * 1024 + ks * 64 + g * 16)) ^ ((unsigned)(q & 7) << 4);
      bfrag A = *(const bfrag*)(smem + ba);
      #pragma unroll
      for (int n = 0; n < 4; ++n) acc[m][n] = MFMA16(A, Bc[n], acc[m][n]);
    }
    __builtin_amdgcn_s_setprio(0);
    if (ks < 15) {
      #pragma unroll
      for (int n = 0; n < 4; ++n) Bc[n] = Bn[n];
    }
  }

  // preload GEMM2 weights + bias (in flight across the barrier + H1 phase)
  bfrag W2r[4];
  #pragma unroll
  for (int i = 0; i < 4; ++i) W2r[i] = w2f[e * 256 + i * 64 + lane];
  float b2v0 = b2[e * 32 + q];
  float b2v1 = b2[e * 32 + 16 + q];
  __syncthreads();                                   // B3 (X dead)

  // ---------------- H1 -> own chunk (sigma: s = q*4+n) ----------------
  {
    float bv[4];
    #pragma unroll
    for (int n = 0; n < 4; ++n) bv[n] = b1[e * 64 + n * 16 + q];
    #pragma unroll
    for (int m = 0; m < 4; ++m) {
      #pragma unroll
      for (int j = 0; j < 4; ++j) {
        float v0 = fmaxf(acc[m][0][j] + bv[0], 0.f);
        float v1 = fmaxf(acc[m][1][j] + bv[1], 0.f);
        float v2 = fmaxf(acc[m][2][j] + bv[2], 0.f);
        float v3 = fmaxf(acc[m][3][j] + bv[3], 0.f);
        int rr = m * 16 + g * 4 + j;
        unsigned byte = cb + (((unsigned)(rr * 128 + q * 8)) ^ ((unsigned)(rr & 7) << 4));
        uint2 p; p.x = pack2(v0, v1); p.y = pack2(v2, v3);
        *(uint2*)(smem + byte) = p;
      }
    }
  }

  // ---------------- GEMM2: K=64 (sigma), N=32 ----------------
  {
    facc a2[4][2];
    #pragma unroll
    for (int m = 0; m < 4; ++m) { a2[m][0] = (facc)0.f; a2[m][1] = (facc)0.f; }
    __builtin_amdgcn_s_setprio(1);
    #pragma unroll
    for (int ks = 0; ks < 2; ++ks) {
      #pragma unroll
      for (int m = 0; m < 4; ++m) {
        unsigned ba = cb + (((unsigned)((m * 16 + q) * 128 + ks * 64 + g * 16)) ^ ((unsigned)(q & 7) << 4));
        bfrag A = *(const bfrag*)(smem + ba);
        #pragma unroll
        for (int n = 0; n < 2; ++n) a2[m][n] = MFMA16(A, W2r[ks * 2 + n], a2[m][n]);
      }
    }
    __builtin_amdgcn_s_setprio(0);
    // preload GEMM3 weights + bias
    bfrag W3r[4];
    #pragma unroll
    for (int n = 0; n < 4; ++n) W3r[n] = w3f[e * 256 + n * 64 + lane];
    float b3v[4];
    #pragma unroll
    for (int n = 0; n < 4; ++n) b3v[n] = b3[e * 64 + n * 16 + q];

    // H2 -> own chunk front (sigma2: s = q*2+n)
    #pragma unroll
    for (int m = 0; m < 4; ++m) {
      #pragma unroll
      for (int j = 0; j < 4; ++j) {
        float v0 = fmaxf(a2[m][0][j] + b2v0, 0.f);
        float v1 = fmaxf(a2[m][1][j] + b2v1, 0.f);
        int rr = m * 16 + g * 4 + j;
        unsigned byte = cb + (((unsigned)(rr * 64 + q * 4)) ^ ((unsigned)(rr & 7) << 4));
        *(unsigned int*)(smem + byte) = pack2(v0, v1);
      }
    }

    // ---------------- GEMM3: K=32 (sigma2), N=64 ----------------
    facc a3[4][4];
    #pragma unroll
    for (int m = 0; m < 4; ++m)
      #pragma unroll
      for (int n = 0; n < 4; ++n) a3[m][n] = (facc)0.f;
    __builtin_amdgcn_s_setprio(1);
    #pragma unroll
    for (int m = 0; m < 4; ++m) {
      unsigned ba = cb + (((unsigned)((m * 16 + q) * 64 + g * 16)) ^ ((unsigned)(q & 7) << 4));
      bfrag A = *(const bfrag*)(smem + ba);
      #pragma unroll
      for (int n = 0; n < 4; ++n) a3[m][n] = MFMA16(A, W3r[n], a3[m][n]);
    }
    __builtin_amdgcn_s_setprio(0);
    // Out -> full own chunk (sigma: s = q*4+n), after all H2 reads (in-order)
    #pragma unroll
    for (int m = 0; m < 4; ++m) {
      #pragma unroll
      for (int j = 0; j < 4; ++j) {
        float v0 = fmaxf(a3[m][0][j] + b3v[0], 0.f);
        float v1 = fmaxf(a3[m][1][j] + b3v[1], 0.f);
        float v2 = fmaxf(a3[m][2][j] + b3v[2], 0.f);
        float v3 = fmaxf(a3[m][3][j] + b3v[3], 0.f);
        int rr = m * 16 + g * 4 + j;
        unsigned byte = cb + (((unsigned)(rr * 128 + q * 8)) ^ ((unsigned)(rr & 7) << 4));
        uint2 p; p.x = pack2(v0, v1); p.y = pack2(v2, v3);
        *(uint2*)(smem + byte) = p;
      }
    }
  }
  __syncthreads();                                   // B4

  // ---------- gacc atomics (overlap with combine's y-writes) ----------
  if (tid < 32) atomicAdd(gacc_out + tid, ((float*)(smem + A_OFF))[tid]);

  // ---------------- combine: LDS recs + weighted sum ----------------
  {
    int tsub = tid >> 4, u = tid & 15;
    const float4* recs = (const float4*)(smem + R_OFF);
    #pragma unroll
    for (int half = 0; half < 2; ++half) {
      int tok = tsub + half * 32;
      size_t trow = (size_t)blockIdx.x * 64 + tok;
      unsigned obyte = ((unsigned)(tok * 128 + u * 8)) ^ ((unsigned)(tok & 7) << 4);
      #pragma unroll
      for (int tt = 0; tt < 2; ++tt) {
        float4 rec = recs[tok * 2 + tt];
        float g1 = rec.x, g2 = rec.y;
        int e1 = __float_as_int(rec.z), e2 = __float_as_int(rec.w);
        uint2 o1 = *(const uint2*)(smem + e1 * 8192 + obyte);
        uint2 o2 = *(const uint2*)(smem + e2 * 8192 + obyte);
        unsigned short s1[4] = { (unsigned short)o1.x, (unsigned short)(o1.x >> 16),
                                 (unsigned short)o1.y, (unsigned short)(o1.y >> 16) };
        unsigned short s2[4] = { (unsigned short)o2.x, (unsigned short)(o2.x >> 16),
                                 (unsigned short)o2.y, (unsigned short)(o2.y >> 16) };
        float* yt = y + (size_t)tt * 4194304 + trow * 64;
        #pragma unroll
        for (int w = 0; w < 4; ++w) {
          // storage col s = 4u+w -> actual col c = w*16 + u
          yt[w * 16 + u] = g1 * bf2f(s1[w]) + g2 * bf2f(s2[w]);
        }
      }
    }
  }

  // ---------- last-block-done: compute cv^2 loss in-kernel ----------
  if (tid == 0) {
    __threadfence();                     // drains this wave's gacc atomics
    unsigned* cnt = (unsigned*)(gacc_out + 32);
    unsigned old = atomicAdd(cnt, 1u);
    if (old == gridDim.x - 1) {
      float loss = 0.f;
      #pragma unroll
      for (int a = 0; a < 4; ++a) {      // [imp t0][imp t1][load t0][load t1]
        float v[8]; float mm = 0.f;
        #pragma unroll
        for (int i = 0; i < 8; ++i) {
          v[i] = __hip_atomic_load(gacc_out + a * 8 + i, __ATOMIC_RELAXED,
                                   __HIP_MEMORY_SCOPE_AGENT);
          mm += v[i];
        }
        mm *= 0.125f;
        float var = 0.f;
        #pragma unroll
        for (int i = 0; i < 8; ++i) { float d = v[i] - mm; var += d * d; }
        loss += (var * (1.f / 7.f)) / (mm * mm + 1e-10f);
      }
      y[8388608] = 0.01f * loss;
    }
  }
}

// ============================ weight repack ================================
//  w1f: [E][16ks][4n][64lane]       B = W1[k][h], h = n*16+q
//  w2f: [E][2ks][2n][64]            K in H1-sigma order: h = (s&3)*16 + (s>>2)
//  w3f: [E][1][4n][64]              K in H2-sigma order: h = (s&1)*16 + (s>>1)
//  wgt: [16 te][512 k] f32          te = t*8+e (exact copy for fp32 gating)
//  also zeroes gacc[32] + done-counter
__global__ __launch_bounds__(256) void moe_prep(
    const float* __restrict__ W1, const float* __restrict__ W2,
    const float* __restrict__ W3, const float* __restrict__ wg,
    bfrag* __restrict__ w1f, bfrag* __restrict__ w2f,
    bfrag* __restrict__ w3f, float* __restrict__ wgt,
    float* __restrict__ gacc)
{
  int tid = blockIdx.x * 256 + threadIdx.x;
  bfrag o;
  if (tid < 32768) {
    int lane = tid & 63, nt = (tid >> 6) & 3, ks = (tid >> 8) & 15, e = tid >> 12;
    int q = lane & 15, g = lane >> 4;
    int hcol = nt * 16 + q;
    #pragma unroll
    for (int j = 0; j < 8; ++j) {
      int k = ks * 32 + g * 8 + j;
      o[j] = (short)bfbits(W1[((e * 512 + k) * 64) + hcol]);
    }
    w1f[tid] = o;
  } else if (tid < 34816) {
    int idx = tid - 32768;
    int lane = idx & 63, nt = (idx >> 6) & 1, ks = (idx >> 7) & 1, e = idx >> 8;
    int q = lane & 15, g = lane >> 4;
    int n = nt * 16 + q;
    #pragma unroll
    for (int j = 0; j < 8; ++j) {
      int s = ks * 32 + g * 8 + j;
      int hh = (s & 3) * 16 + (s >> 2);
      o[j] = (short)bfbits(W2[(e * 64 + hh) * 32 + n]);
    }
    w2f[idx] = o;
  } else if (tid < 36864) {
    int idx = tid - 34816;
    int lane = idx & 63, nt = (idx >> 6) & 3, e = idx >> 8;
    int q = lane & 15, g = lane >> 4;
    int ocol = nt * 16 + q;
    #pragma unroll
    for (int j = 0; j < 8; ++j) {
      int s = g * 8 + j;
      int hh = (s & 1) * 16 + (s >> 1);
      o[j] = (short)bfbits(W3[(e * 32 + hh) * 64 + ocol]);
    }
    w3f[idx] = o;
  } else if (tid < 45056) {
    int idx = tid - 36864;            // te = idx>>9, k = idx&511
    int te = idx >> 9, k = idx & 511;
    wgt[idx] = wg[(((te >> 3) * 512) + k) * 8 + (te & 7)];
  } else if (tid < 45089) {
    gacc[tid - 45056] = 0.f;          // gacc[0..31] + cnt (word 32)
  }
}

extern "C" void kernel_launch(void* const* d_in, const int* in_sizes, int n_in,
                              void* d_out, int out_size, void* d_ws, size_t ws_size,
                              hipStream_t stream) {
  const float* x  = (const float*)d_in[0];
  const float* wg = (const float*)d_in[1];
  const float* bg = (const float*)d_in[2];
  const float* W1 = (const float*)d_in[3];
  const float* b1 = (const float*)d_in[4];
  const float* W2 = (const float*)d_in[5];
  const float* b2 = (const float*)d_in[6];
  const float* W3 = (const float*)d_in[7];
  const float* b3 = (const float*)d_in[8];
  float* y = (float*)d_out;

  char* ws = (char*)d_ws;
  float*  gacc = (float*)ws;                 // 132 B (32 accum + cnt)
  bfrag*  w1f  = (bfrag*)(ws + 256);         // 524288 B
  bfrag*  w2f  = (bfrag*)(ws + 524544);      // 32768 B
  bfrag*  w3f  = (bfrag*)(ws + 557312);      // 32768 B
  float*  wgt  = (float*)(ws + 590080);      // 32768 B

  moe_prep<<<177, 256, 0, stream>>>(W1, W2, W3, wg, w1f, w2f, w3f, wgt, gacc);
  moe_fused<<<1024, 512, 0, stream>>>(x, bg, wgt, b1, b2, b3, w1f, w2f, w3f, gacc, y);
}

// Round 16
// 87.338 us; speedup vs baseline: 4.1042x; 1.3636x over previous
//
#include <hip/hip_runtime.h>

// ---------------------------------------------------------------------------
// Fully-fused Sparse-MMoE forward for MI355X (gfx950), v16 = v8 verbatim.
// B=65536, D=512, E=8, H1=64, H2=32, O=64, T=2, K=2.
//
// v8 is the measured best (87.9us).  All structural escapes attempted in
// v9-v15 regressed, each traced to one structural fact: exact-fp32 gating
// needs x in registers (fr[16]); with the MFMA accumulators this pins the
// kernel at the 128-reg tier (2 blocks/CU), and any added live state spills
// (v6/v9/v12/v14), any x re-read or x-image detour costs more than it saves
// (v4/v10/v11/v13), and setprio starves the cross-block VALU/MFMA overlap
// (v15).  Locking in the best-known configuration.
//
// moe_prep:  weight repack fp32 -> bf16 MFMA B-fragment order (+ wgt fp32
//            transpose copy, + gacc/cnt zeroing).
// moe_fused: 1024 blocks x 512 thr (8 waves = 8 experts), 64 tokens/block.
//            fp32 gating (scalar weight loads) -> top-2 -> bf16 MFMA MLP.
// ---------------------------------------------------------------------------

typedef short bfrag __attribute__((ext_vector_type(8)));   // 8 bf16 = 4 VGPRs
typedef float facc  __attribute__((ext_vector_type(4)));   // 4 f32 accum

#define MFMA16(a, b, c) __builtin_amdgcn_mfma_f32_16x16x32_bf16((a), (b), (c), 0, 0, 0)

__device__ __forceinline__ unsigned short bfbits(float f) {
  unsigned int u = __builtin_bit_cast(unsigned int, f);
  u += 0x7FFFu + ((u >> 16) & 1u);          // RNE
  return (unsigned short)(u >> 16);
}
__device__ __forceinline__ unsigned pack2(float a, float b) {
  return (unsigned)bfbits(a) | ((unsigned)bfbits(b) << 16);
}
__device__ __forceinline__ float bf2f(unsigned short s) {
  unsigned int u = ((unsigned int)s) << 16;
  return __builtin_bit_cast(float, u);
}

// LDS map (bytes):
//  [0,     65536) : gating partials [8w][64tok][16te] f32 (first 32 KB)
//                   -> X tile [64][512] bf16 pitch 1024, XOR ((r&7)<<4)
//                   -> H1/H2/Out wave-private chunks of 8 KB per expert
//  [65536, 70656) : G logits [64][20] f32
//  [70656, 72704) : rec [64 tok][2 task] float4 {g1,g2,e1,e2}
//  [72704, 72832) : lacc [32] f32 (imp t0|imp t1|load t0|load t1)
#define G_OFF   65536
#define R_OFF   70656
#define A_OFF   72704
#define SM_SIZE 72832

__global__ __launch_bounds__(512, 4) void moe_fused(
    const float* __restrict__ x,
    const float* __restrict__ b_gates,
    const float* __restrict__ wgt,      // [16 te][512 k] f32, te = t*8+e
    const float* __restrict__ b1,
    const float* __restrict__ b2,
    const float* __restrict__ b3,
    const bfrag* __restrict__ w1f,
    const bfrag* __restrict__ w2f,
    const bfrag* __restrict__ w3f,
    float* __restrict__ gacc_out,       // [32] + cnt at +32
    float* __restrict__ y)
{
  __shared__ alignas(16) char smem[SM_SIZE];
  const int tid = threadIdx.x;
  const int wave = tid >> 6, lane = tid & 63;
  const int q = lane & 15, g = lane >> 4;
  const int e = wave;                       // 8 waves = 8 experts
  const unsigned cb = (unsigned)e * 8192u;  // own H1/Out chunk

  if (tid < 32) ((float*)(smem + A_OFF))[tid] = 0.f;

  // ---------- load x: lane = token, wave = k-chunk [64w, 64w+64) ----------
  const float* src = x + (size_t)blockIdx.x * 64 * 512 + lane * 512 + wave * 64;
  float4 fr[16];
  #pragma unroll
  for (int j = 0; j < 16; ++j) fr[j] = ((const float4*)src)[j];

  // ---------- gating partial dots: exact fp32, wave-uniform scalar weights ----------
  {
    int wu = __builtin_amdgcn_readfirstlane(wave);
    const float* wbase = wgt + wu * 64;
    float* pp = (float*)(smem + wave * 4096 + lane * 64);
    #pragma unroll
    for (int te = 0; te < 16; ++te) {
      const float* wrow = wbase + te * 512;
      float a0 = 0.f, a1 = 0.f, a2 = 0.f, a3 = 0.f;
      #pragma unroll
      for (int j = 0; j < 16; ++j) {
        a0 = fmaf(fr[j].x, wrow[j * 4 + 0], a0);
        a1 = fmaf(fr[j].y, wrow[j * 4 + 1], a1);
        a2 = fmaf(fr[j].z, wrow[j * 4 + 2], a2);
        a3 = fmaf(fr[j].w, wrow[j * 4 + 3], a3);
      }
      pp[(te + lane) & 15] = (a0 + a1) + (a2 + a3);   // te-rotation: conflict-free
    }
  }
  __syncthreads();                                   // B0

  // ---------- reduce 8 wave-partials -> G logits ----------
  #pragma unroll
  for (int i0 = 0; i0 < 2; ++i0) {
    int i = i0 * 512 + tid;
    int tok = i >> 4, te = i & 15;
    const float* pb = (const float*)smem + tok * 16 + ((te + tok) & 15);
    float s = 0.f;
    #pragma unroll
    for (int w2 = 0; w2 < 8; ++w2) s += pb[w2 * 1024];
    ((float*)(smem + G_OFF))[tok * 20 + te] = s + b_gates[te];
  }
  __syncthreads();                                   // B1 (partials dead)

  // ---------- stage X tile from registers (overwrites partials region) ----------
  #pragma unroll
  for (int p = 0; p < 8; ++p) {
    uint4 v;
    v.x = pack2(fr[2 * p].x, fr[2 * p].y);
    v.y = pack2(fr[2 * p].z, fr[2 * p].w);
    v.z = pack2(fr[2 * p + 1].x, fr[2 * p + 1].y);
    v.w = pack2(fr[2 * p + 1].z, fr[2 * p + 1].w);
    unsigned byte = ((unsigned)(lane * 1024 + wave * 128 + p * 16)) ^ ((unsigned)(lane & 7) << 4);
    *(uint4*)(smem + byte) = v;
  }

  // ---------- top-2 + softmax -> LDS recs + imp/load atomics ----------
  if (tid < 128) {
    int tok = tid >> 1, task = tid & 1;
    const float* Gr = (const float*)(smem + G_OFF) + tok * 20 + task * 8;
    float l[8];
    #pragma unroll
    for (int ee = 0; ee < 8; ++ee) l[ee] = Gr[ee];
    float v1 = l[0]; int e1 = 0;
    #pragma unroll
    for (int ee = 1; ee < 8; ++ee) { if (l[ee] > v1) { v1 = l[ee]; e1 = ee; } }
    float v2 = -3.4e38f; int e2 = 0;
    #pragma unroll
    for (int ee = 0; ee < 8; ++ee) {
      if (ee != e1 && l[ee] > v2) { v2 = l[ee]; e2 = ee; }
    }
    float g1 = 1.f / (1.f + __expf(v2 - v1));
    float g2 = 1.f - g1;
    float4 rec;
    rec.x = g1; rec.y = g2;
    rec.z = __int_as_float(e1); rec.w = __int_as_float(e2);
    ((float4*)(smem + R_OFF))[tok * 2 + task] = rec;
    float* lacc = (float*)(smem + A_OFF);
    atomicAdd(lacc + task * 8 + e1, g1);
    atomicAdd(lacc + task * 8 + e2, g2);
    atomicAdd(lacc + 16 + task * 8 + e1, 1.f);
    atomicAdd(lacc + 16 + task * 8 + e2, 1.f);
  }
  __syncthreads();                                   // B2 (X staged)

  // ---------------- GEMM1: 64 tok x 64 h1, K=512, depth-1 B prefetch ------
  facc acc[4][4];
  #pragma unroll
  for (int m = 0; m < 4; ++m)
    #pragma unroll
    for (int n = 0; n < 4; ++n) acc[m][n] = (facc)0.f;

  const bfrag* w1e = w1f + e * 4096 + lane;
  bfrag Bc[4], Bn[4];
  #pragma unroll
  for (int n = 0; n < 4; ++n) Bc[n] = w1e[n * 64];
  #pragma unroll
  for (int ks = 0; ks < 16; ++ks) {
    if (ks < 15) {
      #pragma unroll
      for (int n = 0; n < 4; ++n) Bn[n] = w1e[(ks + 1) * 256 + n * 64];
    }
    #pragma unroll
    for (int m = 0; m < 4; ++m) {
      unsigned ba = ((unsigned)((m * 16 + q) * 1024 + ks * 64 + g * 16)) ^ ((unsigned)(q & 7) << 4);
      bfrag A = *(const bfrag*)(smem + ba);
      #pragma unroll
      for (int n = 0; n < 4; ++n) acc[m][n] = MFMA16(A, Bc[n], acc[m][n]);
    }
    if (ks < 15) {
      #pragma unroll
      for (int n = 0; n < 4; ++n) Bc[n] = Bn[n];
    }
  }

  // preload GEMM2 weights + bias (in flight across the barrier + H1 phase)
  bfrag W2r[4];
  #pragma unroll
  for (int i = 0; i < 4; ++i) W2r[i] = w2f[e * 256 + i * 64 + lane];
  float b2v0 = b2[e * 32 + q];
  float b2v1 = b2[e * 32 + 16 + q];
  __syncthreads();                                   // B3 (X dead)

  // ---------------- H1 -> own chunk (sigma: s = q*4+n) ----------------
  {
    float bv[4];
    #pragma unroll
    for (int n = 0; n < 4; ++n) bv[n] = b1[e * 64 + n * 16 + q];
    #pragma unroll
    for (int m = 0; m < 4; ++m) {
      #pragma unroll
      for (int j = 0; j < 4; ++j) {
        float v0 = fmaxf(acc[m][0][j] + bv[0], 0.f);
        float v1 = fmaxf(acc[m][1][j] + bv[1], 0.f);
        float v2 = fmaxf(acc[m][2][j] + bv[2], 0.f);
        float v3 = fmaxf(acc[m][3][j] + bv[3], 0.f);
        int rr = m * 16 + g * 4 + j;
        unsigned byte = cb + (((unsigned)(rr * 128 + q * 8)) ^ ((unsigned)(rr & 7) << 4));
        uint2 p; p.x = pack2(v0, v1); p.y = pack2(v2, v3);
        *(uint2*)(smem + byte) = p;
      }
    }
  }

  // ---------------- GEMM2: K=64 (sigma), N=32 ----------------
  {
    facc a2[4][2];
    #pragma unroll
    for (int m = 0; m < 4; ++m) { a2[m][0] = (facc)0.f; a2[m][1] = (facc)0.f; }
    #pragma unroll
    for (int ks = 0; ks < 2; ++ks) {
      #pragma unroll
      for (int m = 0; m < 4; ++m) {
        unsigned ba = cb + (((unsigned)((m * 16 + q) * 128 + ks * 64 + g * 16)) ^ ((unsigned)(q & 7) << 4));
        bfrag A = *(const bfrag*)(smem + ba);
        #pragma unroll
        for (int n = 0; n < 2; ++n) a2[m][n] = MFMA16(A, W2r[ks * 2 + n], a2[m][n]);
      }
    }
    // preload GEMM3 weights + bias
    bfrag W3r[4];
    #pragma unroll
    for (int n = 0; n < 4; ++n) W3r[n] = w3f[e * 256 + n * 64 + lane];
    float b3v[4];
    #pragma unroll
    for (int n = 0; n < 4; ++n) b3v[n] = b3[e * 64 + n * 16 + q];

    // H2 -> own chunk front (sigma2: s = q*2+n)
    #pragma unroll
    for (int m = 0; m < 4; ++m) {
      #pragma unroll
      for (int j = 0; j < 4; ++j) {
        float v0 = fmaxf(a2[m][0][j] + b2v0, 0.f);
        float v1 = fmaxf(a2[m][1][j] + b2v1, 0.f);
        int rr = m * 16 + g * 4 + j;
        unsigned byte = cb + (((unsigned)(rr * 64 + q * 4)) ^ ((unsigned)(rr & 7) << 4));
        *(unsigned int*)(smem + byte) = pack2(v0, v1);
      }
    }

    // ---------------- GEMM3: K=32 (sigma2), N=64 ----------------
    facc a3[4][4];
    #pragma unroll
    for (int m = 0; m < 4; ++m)
      #pragma unroll
      for (int n = 0; n < 4; ++n) a3[m][n] = (facc)0.f;
    #pragma unroll
    for (int m = 0; m < 4; ++m) {
      unsigned ba = cb + (((unsigned)((m * 16 + q) * 64 + g * 16)) ^ ((unsigned)(q & 7) << 4));
      bfrag A = *(const bfrag*)(smem + ba);
      #pragma unroll
      for (int n = 0; n < 4; ++n) a3[m][n] = MFMA16(A, W3r[n], a3[m][n]);
    }
    // Out -> full own chunk (sigma: s = q*4+n), after all H2 reads (in-order)
    #pragma unroll
    for (int m = 0; m < 4; ++m) {
      #pragma unroll
      for (int j = 0; j < 4; ++j) {
        float v0 = fmaxf(a3[m][0][j] + b3v[0], 0.f);
        float v1 = fmaxf(a3[m][1][j] + b3v[1], 0.f);
        float v2 = fmaxf(a3[m][2][j] + b3v[2], 0.f);
        float v3 = fmaxf(a3[m][3][j] + b3v[3], 0.f);
        int rr = m * 16 + g * 4 + j;
        unsigned byte = cb + (((unsigned)(rr * 128 + q * 8)) ^ ((unsigned)(rr & 7) << 4));
        uint2 p; p.x = pack2(v0, v1); p.y = pack2(v2, v3);
        *(uint2*)(smem + byte) = p;
      }
    }
  }
  __syncthreads();                                   // B4

  // ---------------- combine: LDS recs + weighted sum ----------------
  {
    int tsub = tid >> 4, u = tid & 15;
    const float4* recs = (const float4*)(smem + R_OFF);
    #pragma unroll
    for (int half = 0; half < 2; ++half) {
      int tok = tsub + half * 32;
      size_t trow = (size_t)blockIdx.x * 64 + tok;
      unsigned obyte = ((unsigned)(tok * 128 + u * 8)) ^ ((unsigned)(tok & 7) << 4);
      #pragma unroll
      for (int tt = 0; tt < 2; ++tt) {
        float4 rec = recs[tok * 2 + tt];
        float g1 = rec.x, g2 = rec.y;
        int e1 = __float_as_int(rec.z), e2 = __float_as_int(rec.w);
        uint2 o1 = *(const uint2*)(smem + e1 * 8192 + obyte);
        uint2 o2 = *(const uint2*)(smem + e2 * 8192 + obyte);
        unsigned short s1[4] = { (unsigned short)o1.x, (unsigned short)(o1.x >> 16),
                                 (unsigned short)o1.y, (unsigned short)(o1.y >> 16) };
        unsigned short s2[4] = { (unsigned short)o2.x, (unsigned short)(o2.x >> 16),
                                 (unsigned short)o2.y, (unsigned short)(o2.y >> 16) };
        float* yt = y + (size_t)tt * 4194304 + trow * 64;
        #pragma unroll
        for (int w = 0; w < 4; ++w) {
          // storage col s = 4u+w -> actual col c = w*16 + u
          yt[w * 16 + u] = g1 * bf2f(s1[w]) + g2 * bf2f(s2[w]);
        }
      }
    }
  }
  if (tid < 32) atomicAdd(gacc_out + tid, ((float*)(smem + A_OFF))[tid]);
  __syncthreads();                                   // B5: block's atomics drained

  // ---------- last-block-done: compute cv^2 loss in-kernel ----------
  if (tid == 0) {
    unsigned* cnt = (unsigned*)(gacc_out + 32);
    unsigned old = atomicAdd(cnt, 1u);
    if (old == gridDim.x - 1) {
      float loss = 0.f;
      #pragma unroll
      for (int a = 0; a < 4; ++a) {      // [imp t0][imp t1][load t0][load t1]
        float v[8]; float mm = 0.f;
        #pragma unroll
        for (int i = 0; i < 8; ++i) {
          v[i] = __hip_atomic_load(gacc_out + a * 8 + i, __ATOMIC_RELAXED,
                                   __HIP_MEMORY_SCOPE_AGENT);
          mm += v[i];
        }
        mm *= 0.125f;
        float var = 0.f;
        #pragma unroll
        for (int i = 0; i < 8; ++i) { float d = v[i] - mm; var += d * d; }
        loss += (var * (1.f / 7.f)) / (mm * mm + 1e-10f);
      }
      y[8388608] = 0.01f * loss;
    }
  }
}

// ============================ weight repack ================================
//  w1f: [E][16ks][4n][64lane]       B = W1[k][h], h = n*16+q
//  w2f: [E][2ks][2n][64]            K in H1-sigma order: h = (s&3)*16 + (s>>2)
//  w3f: [E][1][4n][64]              K in H2-sigma order: h = (s&1)*16 + (s>>1)
//  wgt: [16 te][512 k] f32          te = t*8+e (exact copy for fp32 gating)
//  also zeroes gacc[32] + done-counter
__global__ __launch_bounds__(256) void moe_prep(
    const float* __restrict__ W1, const float* __restrict__ W2,
    const float* __restrict__ W3, const float* __restrict__ wg,
    bfrag* __restrict__ w1f, bfrag* __restrict__ w2f,
    bfrag* __restrict__ w3f, float* __restrict__ wgt,
    float* __restrict__ gacc)
{
  int tid = blockIdx.x * 256 + threadIdx.x;
  bfrag o;
  if (tid < 32768) {
    int lane = tid & 63, nt = (tid >> 6) & 3, ks = (tid >> 8) & 15, e = tid >> 12;
    int q = lane & 15, g = lane >> 4;
    int hcol = nt * 16 + q;
    #pragma unroll
    for (int j = 0; j < 8; ++j) {
      int k = ks * 32 + g * 8 + j;
      o[j] = (short)bfbits(W1[((e * 512 + k) * 64) + hcol]);
    }
    w1f[tid] = o;
  } else if (tid < 34816) {
    int idx = tid - 32768;
    int lane = idx & 63, nt = (idx >> 6) & 1, ks = (idx >> 7) & 1, e = idx >> 8;
    int q = lane & 15, g = lane >> 4;
    int n = nt * 16 + q;
    #pragma unroll
    for (int j = 0; j < 8; ++j) {
      int s = ks * 32 + g * 8 + j;
      int hh = (s & 3) * 16 + (s >> 2);
      o[j] = (short)bfbits(W2[(e * 64 + hh) * 32 + n]);
    }
    w2f[idx] = o;
  } else if (tid < 36864) {
    int idx = tid - 34816;
    int lane = idx & 63, nt = (idx >> 6) & 3, e = idx >> 8;
    int q = lane & 15, g = lane >> 4;
    int ocol = nt * 16 + q;
    #pragma unroll
    for (int j = 0; j < 8; ++j) {
      int s = g * 8 + j;
      int hh = (s & 1) * 16 + (s >> 1);
      o[j] = (short)bfbits(W3[(e * 32 + hh) * 64 + ocol]);
    }
    w3f[idx] = o;
  } else if (tid < 45056) {
    int idx = tid - 36864;            // te = idx>>9, k = idx&511
    int te = idx >> 9, k = idx & 511;
    wgt[idx] = wg[(((te >> 3) * 512) + k) * 8 + (te & 7)];
  } else if (tid < 45089) {
    gacc[tid - 45056] = 0.f;          // gacc[0..31] + cnt (word 32)
  }
}

extern "C" void kernel_launch(void* const* d_in, const int* in_sizes, int n_in,
                              void* d_out, int out_size, void* d_ws, size_t ws_size,
                              hipStream_t stream) {
  const float* x  = (const float*)d_in[0];
  const float* wg = (const float*)d_in[1];
  const float* bg = (const float*)d_in[2];
  const float* W1 = (const float*)d_in[3];
  const float* b1 = (const float*)d_in[4];
  const float* W2 = (const float*)d_in[5];
  const float* b2 = (const float*)d_in[6];
  const float* W3 = (const float*)d_in[7];
  const float* b3 = (const float*)d_in[8];
  float* y = (float*)d_out;

  char* ws = (char*)d_ws;
  float*  gacc = (float*)ws;                 // 132 B (32 accum + cnt)
  bfrag*  w1f  = (bfrag*)(ws + 256);         // 524288 B
  bfrag*  w2f  = (bfrag*)(ws + 524544);      // 32768 B
  bfrag*  w3f  = (bfrag*)(ws + 557312);      // 32768 B
  float*  wgt  = (float*)(ws + 590080);      // 32768 B

  moe_prep<<<177, 256, 0, stream>>>(W1, W2, W3, wg, w1f, w2f, w3f, wgt, gacc);
  moe_fused<<<1024, 512, 0, stream>>>(x, bg, wgt, b1, b2, b3, w1f, w2f, w3f, gacc, y);
}